// Round 1
// baseline (16475.716 us; speedup 1.0000x reference)
//
#include <hip/hip_runtime.h>
#include <cmath>

// Problem constants
static constexpr int Bb  = 4;
static constexpr int S   = 2048;
static constexpr int DIN = 4096;
static constexpr int P   = 512;    // D_PROJ == D_MEM
static constexpr int AST = 512;    // assistant_start
static constexpr int TR  = 1536;   // run length
static constexpr int NWG = 32;     // scan workgroups (16 U-columns each)
#define DTC (1.0f/1535.0f)

// Workspace layout (float element offsets)
static constexpr size_t SZ      = (size_t)Bb * S * P;          // 4,194,304
static constexpr size_t GXSZ    = (size_t)TR * Bb * P;         // 3,145,728
static constexpr size_t OFF_Q   = 0;
static constexpr size_t OFF_K   = SZ;
static constexpr size_t OFF_V   = 2 * SZ;
static constexpr size_t OFF_GXZ = 0;                           // reuses Q/K/V after attention
static constexpr size_t OFF_GXR = GXSZ;
static constexpr size_t OFF_GXH = 2 * GXSZ;
static constexpr size_t OFF_FEAT= 3 * GXSZ + (size_t)(TR + 1) * Bb * P; // after old h-hist slot
static constexpr size_t OFF_SC  = OFF_FEAT + SZ;               // scores/attn; tagged bufs live here in scan phase

#define INNER16 \
  acc[0][0] += af.x*bf.x; acc[0][1] += af.x*bf.y; acc[0][2] += af.x*bf.z; acc[0][3] += af.x*bf.w; \
  acc[1][0] += af.y*bf.x; acc[1][1] += af.y*bf.y; acc[1][2] += af.y*bf.z; acc[1][3] += af.y*bf.w; \
  acc[2][0] += af.z*bf.x; acc[2][1] += af.z*bf.y; acc[2][2] += af.z*bf.z; acc[2][3] += af.z*bf.w; \
  acc[3][0] += af.w*bf.x; acc[3][1] += af.w*bf.y; acc[3][2] += af.w*bf.z; acc[3][3] += af.w*bf.w;

__global__ __launch_bounds__(256) void k_zero(float* p, int n) {
  int i = blockIdx.x * 256 + threadIdx.x;
  if (i < n) p[i] = 0.f;
}

// Fill tagged-word buffers with an impossible tag (0xFFFFFFFF) so stale data
// from a previous launch/graph-replay can never match a step tag.
__global__ __launch_bounds__(256) void k_tagclear(unsigned long long* p, int n) {
  int i = blockIdx.x * 256 + threadIdx.x;
  if (i < n) p[i] = 0xFFFFFFFF00000000ULL;
}

// ---------------- QKV projection: (8192 x 4096) @ (4096 x 512) + bias, z selects Q/K/V
__global__ __launch_bounds__(256) void k_qkv(
    const float* __restrict__ x,
    const float* __restrict__ W0, const float* __restrict__ W1, const float* __restrict__ W2,
    const float* __restrict__ b0, const float* __restrict__ b1, const float* __restrict__ b2,
    float* __restrict__ O0, float* __restrict__ O1, float* __restrict__ O2)
{
  __shared__ float As[32][68];  // transposed A tile: As[k][m]
  __shared__ float Bs[32][64];
  const int z = blockIdx.z;
  const float* W    = (z == 0) ? W0 : (z == 1) ? W1 : W2;
  const float* bias = (z == 0) ? b0 : (z == 1) ? b1 : b2;
  float* Out        = (z == 0) ? O0 : (z == 1) ? O1 : O2;
  const int tid = threadIdx.x;
  const int m0 = blockIdx.y * 64, n0 = blockIdx.x * 64;
  const int tm = tid >> 4, tn = tid & 15;
  const int la_m = tid >> 3;
  const int la_k = (tid & 7) << 2;
  const int lb_k = tid >> 4;
  const int lb_n = (tid & 15) << 2;
  float acc[4][4] = {};
  for (int k0 = 0; k0 < DIN; k0 += 32) {
#pragma unroll
    for (int pp = 0; pp < 2; ++pp) {
      int m = la_m + pp * 32;
      float4 v = *(const float4*)(x + (size_t)(m0 + m) * DIN + k0 + la_k);
      As[la_k + 0][m] = v.x; As[la_k + 1][m] = v.y; As[la_k + 2][m] = v.z; As[la_k + 3][m] = v.w;
    }
#pragma unroll
    for (int pp = 0; pp < 2; ++pp) {
      int k = lb_k + pp * 16;
      *(float4*)&Bs[k][lb_n] = *(const float4*)(W + (size_t)(k0 + k) * P + n0 + lb_n);
    }
    __syncthreads();
#pragma unroll
    for (int kk = 0; kk < 32; ++kk) {
      float4 af = *(float4*)&As[kk][tm << 2];
      float4 bf = *(float4*)&Bs[kk][tn << 2];
      INNER16
    }
    __syncthreads();
  }
  float4 bv = *(const float4*)(bias + n0 + (tn << 2));
#pragma unroll
  for (int i = 0; i < 4; ++i) {
    int row = m0 + (tm << 2) + i;
    float4 o = make_float4(acc[i][0] + bv.x, acc[i][1] + bv.y, acc[i][2] + bv.z, acc[i][3] + bv.w);
    *(float4*)(Out + (size_t)row * P + n0 + (tn << 2)) = o;
  }
}

// ---------------- scores = Q @ K^T / scale, causal mask (only tiles jt <= qt computed)
__global__ __launch_bounds__(256) void k_scores(
    const float* __restrict__ Q, const float* __restrict__ Km, float* __restrict__ Sc)
{
  const int jt = blockIdx.x, qt = blockIdx.y, b = blockIdx.z;
  if (jt > qt) return;
  __shared__ float As[32][68];  // Q^T: As[k][i]
  __shared__ float Bs[32][68];  // K^T: Bs[k][j]
  const float* Qb = Q + (size_t)b * S * P;
  const float* Kb = Km + (size_t)b * S * P;
  const int tid = threadIdx.x;
  const int i0 = qt * 64, j0 = jt * 64;
  const int tm = tid >> 4, tn = tid & 15;
  const int lr = tid >> 3;
  const int lk = (tid & 7) << 2;
  float acc[4][4] = {};
  for (int k0 = 0; k0 < P; k0 += 32) {
#pragma unroll
    for (int pp = 0; pp < 2; ++pp) {
      int r = lr + pp * 32;
      float4 v = *(const float4*)(Qb + (size_t)(i0 + r) * P + k0 + lk);
      As[lk + 0][r] = v.x; As[lk + 1][r] = v.y; As[lk + 2][r] = v.z; As[lk + 3][r] = v.w;
      float4 w = *(const float4*)(Kb + (size_t)(j0 + r) * P + k0 + lk);
      Bs[lk + 0][r] = w.x; Bs[lk + 1][r] = w.y; Bs[lk + 2][r] = w.z; Bs[lk + 3][r] = w.w;
    }
    __syncthreads();
#pragma unroll
    for (int kk = 0; kk < 32; ++kk) {
      float4 af = *(float4*)&As[kk][tm << 2];
      float4 bf = *(float4*)&Bs[kk][tn << 2];
      INNER16
    }
    __syncthreads();
  }
  const float invs = 0.04419417382f;  // 1/sqrt(512+1e-6)
#pragma unroll
  for (int i = 0; i < 4; ++i) {
    int ig = i0 + (tm << 2) + i;
    float v0 = acc[i][0] * invs, v1 = acc[i][1] * invs, v2 = acc[i][2] * invs, v3 = acc[i][3] * invs;
    int jg = j0 + (tn << 2);
    if (jg + 0 > ig) v0 = -1e9f;
    if (jg + 1 > ig) v1 = -1e9f;
    if (jg + 2 > ig) v2 = -1e9f;
    if (jg + 3 > ig) v3 = -1e9f;
    *(float4*)(Sc + (size_t)b * S * S + (size_t)ig * S + jg) = make_float4(v0, v1, v2, v3);
  }
}

// ---------------- row softmax over [0, i], zero-fill to end of diagonal tile (in place)
__global__ __launch_bounds__(256) void k_softmax(float* __restrict__ Sc)
{
  const int i = blockIdx.x, b = blockIdx.y;
  float* row = Sc + (size_t)b * S * S + (size_t)i * S;
  __shared__ float sv[2048];
  __shared__ float red[256];
  const int tid = threadIdx.x;
  const int len = i + 1;
  float lmax = -1e30f;
  for (int k = tid; k < len; k += 256) { float v = row[k]; sv[k] = v; lmax = fmaxf(lmax, v); }
  red[tid] = lmax; __syncthreads();
  for (int s = 128; s > 0; s >>= 1) { if (tid < s) red[tid] = fmaxf(red[tid], red[tid + s]); __syncthreads(); }
  const float m = red[0]; __syncthreads();
  float lsum = 0.f;
  for (int k = tid; k < len; k += 256) { float e = expf(sv[k] - m); sv[k] = e; lsum += e; }
  red[tid] = lsum; __syncthreads();
  for (int s = 128; s > 0; s >>= 1) { if (tid < s) red[tid] += red[tid + s]; __syncthreads(); }
  const float inv = 1.0f / red[0];
  for (int k = tid; k < len; k += 256) row[k] = sv[k] * inv;
  const int tail = ((i >> 6) + 1) << 6;
  for (int k = len + tid; k < tail; k += 256) row[k] = 0.f;
}

// ---------------- feat = attn @ V (skip upper-triangle tiles)
__global__ __launch_bounds__(256) void k_attnv(
    const float* __restrict__ At, const float* __restrict__ V, float* __restrict__ F)
{
  __shared__ float As[32][68];
  __shared__ float Bs[32][64];
  const int qt = blockIdx.y, b = blockIdx.z;
  const float* Ab = At + (size_t)b * S * S;
  const float* Vb = V + (size_t)b * S * P;
  const int tid = threadIdx.x;
  const int m0 = qt * 64, n0 = blockIdx.x * 64;
  const int tm = tid >> 4, tn = tid & 15;
  const int la_m = tid >> 3;
  const int la_k = (tid & 7) << 2;
  const int lb_k = tid >> 4;
  const int lb_n = (tid & 15) << 2;
  float acc[4][4] = {};
  const int kext = (qt + 1) * 64;
  for (int k0 = 0; k0 < kext; k0 += 32) {
#pragma unroll
    for (int pp = 0; pp < 2; ++pp) {
      int m = la_m + pp * 32;
      float4 v = *(const float4*)(Ab + (size_t)(m0 + m) * S + k0 + la_k);
      As[la_k + 0][m] = v.x; As[la_k + 1][m] = v.y; As[la_k + 2][m] = v.z; As[la_k + 3][m] = v.w;
    }
#pragma unroll
    for (int pp = 0; pp < 2; ++pp) {
      int k = lb_k + pp * 16;
      *(float4*)&Bs[k][lb_n] = *(const float4*)(Vb + (size_t)(k0 + k) * P + n0 + lb_n);
    }
    __syncthreads();
#pragma unroll
    for (int kk = 0; kk < 32; ++kk) {
      float4 af = *(float4*)&As[kk][tm << 2];
      float4 bf = *(float4*)&Bs[kk][tn << 2];
      INNER16
    }
    __syncthreads();
  }
#pragma unroll
  for (int i = 0; i < 4; ++i) {
    int row = m0 + (tm << 2) + i;
    *(float4*)(F + (size_t)b * S * P + (size_t)row * P + n0 + (tn << 2)) =
        make_float4(acc[i][0], acc[i][1], acc[i][2], acc[i][3]);
  }
}

// ---------------- gx = feat_assist @ {Wz,Wr,Wh} + bias; output layout [t][b][j]
__global__ __launch_bounds__(256) void k_gx(
    const float* __restrict__ feat,
    const float* __restrict__ Wz, const float* __restrict__ Wr, const float* __restrict__ Wh,
    const float* __restrict__ bz, const float* __restrict__ br, const float* __restrict__ bh,
    float* __restrict__ gz, float* __restrict__ gr, float* __restrict__ gh)
{
  __shared__ float As[32][68];
  __shared__ float Bs[32][64];
  const int z = blockIdx.z;
  const float* W    = (z == 0) ? Wz : (z == 1) ? Wr : Wh;
  const float* bias = (z == 0) ? bz : (z == 1) ? br : bh;
  float* Out        = (z == 0) ? gz : (z == 1) ? gr : gh;
  const int tid = threadIdx.x;
  const int m0 = blockIdx.y * 64, n0 = blockIdx.x * 64;
  const int bb = m0 / TR;
  const int t0 = m0 - bb * TR;
  const float* Arow = feat + ((size_t)(bb * S + AST + t0)) * P;  // 64 consecutive rows
  const int tm = tid >> 4, tn = tid & 15;
  const int la_m = tid >> 3;
  const int la_k = (tid & 7) << 2;
  const int lb_k = tid >> 4;
  const int lb_n = (tid & 15) << 2;
  float acc[4][4] = {};
  for (int k0 = 0; k0 < P; k0 += 32) {
#pragma unroll
    for (int pp = 0; pp < 2; ++pp) {
      int m = la_m + pp * 32;
      float4 v = *(const float4*)(Arow + (size_t)m * P + k0 + la_k);
      As[la_k + 0][m] = v.x; As[la_k + 1][m] = v.y; As[la_k + 2][m] = v.z; As[la_k + 3][m] = v.w;
    }
#pragma unroll
    for (int pp = 0; pp < 2; ++pp) {
      int k = lb_k + pp * 16;
      *(float4*)&Bs[k][lb_n] = *(const float4*)(W + (size_t)(k0 + k) * P + n0 + lb_n);
    }
    __syncthreads();
#pragma unroll
    for (int kk = 0; kk < 32; ++kk) {
      float4 af = *(float4*)&As[kk][tm << 2];
      float4 bf = *(float4*)&Bs[kk][tn << 2];
      INNER16
    }
    __syncthreads();
  }
  float4 bv = *(const float4*)(bias + n0 + (tn << 2));
#pragma unroll
  for (int i = 0; i < 4; ++i) {
    int t = t0 + (tm << 2) + i;
    float4 o = make_float4(acc[i][0] + bv.x, acc[i][1] + bv.y, acc[i][2] + bv.z, acc[i][3] + bv.w);
    *(float4*)(Out + ((size_t)t * 4 + bb) * P + n0 + (tn << 2)) = o;
  }
}

// ---------------- attention pooling over prefix + h0; writes tagged h(0) (tag=0)
__global__ __launch_bounds__(256) void k_pool(
    const float* __restrict__ feat, const float* __restrict__ Wscore,
    const float* __restrict__ Wp2h, const float* __restrict__ bp2h,
    unsigned long long* __restrict__ hT)
{
  const int b = blockIdx.x;
  const float* fb = feat + (size_t)b * S * P;  // prefix rows 0..511
  __shared__ float sw[512];
  __shared__ float pool[512];
  __shared__ float red[256];
  const int tid = threadIdx.x;
  for (int u = tid; u < 512; u += 256) {
    float s = 0.f;
    for (int p4 = 0; p4 < P; p4 += 4) {
      float4 f = *(const float4*)(fb + (size_t)u * P + p4);
      float4 w = *(const float4*)(Wscore + p4);
      s += f.x * w.x + f.y * w.y + f.z * w.z + f.w * w.w;
    }
    sw[u] = s;
  }
  __syncthreads();
  float lm = fmaxf(sw[tid], sw[tid + 256]);
  red[tid] = lm; __syncthreads();
  for (int s = 128; s > 0; s >>= 1) { if (tid < s) red[tid] = fmaxf(red[tid], red[tid + s]); __syncthreads(); }
  const float m = red[0]; __syncthreads();
  float e0 = expf(sw[tid] - m), e1 = expf(sw[tid + 256] - m);
  sw[tid] = e0; sw[tid + 256] = e1;
  red[tid] = e0 + e1; __syncthreads();
  for (int s = 128; s > 0; s >>= 1) { if (tid < s) red[tid] += red[tid + s]; __syncthreads(); }
  const float inv = 1.0f / red[0];
  __syncthreads();
  sw[tid] *= inv; sw[tid + 256] *= inv;
  __syncthreads();
  for (int p = tid; p < P; p += 256) {
    float a = 0.f;
    for (int u = 0; u < 512; ++u) a += sw[u] * fb[(size_t)u * P + p];
    pool[p] = a;
  }
  __syncthreads();
  for (int j = tid; j < P; j += 256) {
    float a = bp2h[j];
    for (int p = 0; p < P; ++p) a += pool[p] * Wp2h[(size_t)p * P + j];
    // tagged word: tag (hi) = 0, value (lo) = f32 bits of h0
    hT[(size_t)b * 512 + j] = (unsigned long long)__float_as_uint(tanhf(a));
  }
}

// Poll a 2048-word tagged slot (4 batches x 512) until every word carries `tag`,
// depositing values into hb[4][516] (flat pointer hbp, row stride 516).
// Tag and value share one 8-byte atomic word -> seeing the tag implies seeing
// the value; no flags, no fences, no L2 flush.
__device__ __forceinline__ void poll_slot(const unsigned long long* __restrict__ src,
                                          unsigned tag, float* __restrict__ hbp, int tid)
{
  unsigned long long v[8];
  unsigned need = 0xFFu;
  while (need) {
    unsigned still = 0u;
#pragma unroll
    for (int k = 0; k < 8; ++k) {
      if (need & (1u << k)) {
        unsigned long long u = __hip_atomic_load(src + ((k << 8) | tid),
                                                 __ATOMIC_RELAXED, __HIP_MEMORY_SCOPE_AGENT);
        if ((unsigned)(u >> 32) == tag) v[k] = u;
        else still |= (1u << k);
      }
    }
    need = still;
  }
#pragma unroll
  for (int k = 0; k < 8; ++k) {
    int idx = (k << 8) | tid;               // word index in [0,2048)
    hbp[(idx >> 9) * 516 + (idx & 511)] = __uint_as_float((unsigned)v[k]);
  }
}

// xor-butterfly reduce of 4 batch accumulators across a 2^LOG2N-lane group.
// Result: group-lane l holds acc[l&3] summed over the whole group (5 or 6
// shuffles instead of 4*LOG2N; replaces the conflicted LDS red[] roundtrip).
template<int LOG2N>
__device__ __forceinline__ float xreduce4(float a0, float a1, float a2, float a3, int lane)
{
  float s01 = (lane & 1) ? a0 : a1;
  float r01 = __shfl_xor(s01, 1);
  float x0  = ((lane & 1) ? a1 : a0) + r01;   // even lanes: a0-pair; odd: a1-pair
  float s23 = (lane & 1) ? a2 : a3;
  float r23 = __shfl_xor(s23, 1);
  float x2  = ((lane & 1) ? a3 : a2) + r23;   // even lanes: a2-pair; odd: a3-pair
  float s   = (lane & 2) ? x0 : x2;
  float r   = __shfl_xor(s, 2);
  float v   = ((lane & 2) ? x2 : x0) + r;     // lane&3 == b holds acc b over 4 lanes
#pragma unroll
  for (int m = 4; m < (1 << LOG2N); m <<= 1) v += __shfl_xor(v, m);
  return v;
}

// ---------------- persistent GRU scan: 32 WGs, 16 U-columns each.
// Cross-WG sync: tagged 8-byte words ({step : f32}) in a depth-2 double buffer
// at AGENT scope. Consumers poll the data words directly - the tag match IS
// the readiness signal (no flag counters, no __threadfence, no bulk reload).
// Depth-2 safety: publishing h(t+1)/rh(t+1) transitively requires every WG to
// have fully consumed h(t-1)/rh(t-1) (the interleaved all-gathers order it).
__global__ __launch_bounds__(256) void k_scan(
    const float* __restrict__ Uz, const float* __restrict__ Ur, const float* __restrict__ Uh,
    const float* __restrict__ gz, const float* __restrict__ gr, const float* __restrict__ gh,
    const float* __restrict__ Wmem, const float* __restrict__ bmem,
    unsigned long long* __restrict__ hT, unsigned long long* __restrict__ rhT,
    float* __restrict__ out)
{
  __shared__ float Us[3][2][8][520];
  __shared__ float hb[4][516];
  __shared__ float zloc[2][4][8];
  __shared__ float hploc[2][4][8];
  __shared__ float holoc[2][4][8];
  const int wg = blockIdx.x;
  const int tid = threadIdx.x;
  const int j0 = wg * 16;

  for (int idx = tid; idx < 3 * 512 * 16; idx += 256) {
    int mt = idx >> 13;                // 8192 elements per matrix
    int rem = idx & 8191;
    int i = rem >> 4, c = rem & 15;
    const float* U = (mt == 0) ? Uz : (mt == 1) ? Ur : Uh;
    Us[mt][c >> 3][c & 7][i] = U[(size_t)i * P + j0 + c];
  }
  float wmv0 = 0.f, wmv1 = 0.f;
  if (tid < 32) { int c = tid >> 2; wmv0 = Wmem[j0 + c]; wmv1 = Wmem[j0 + 8 + c]; }
  const float bmv = bmem[0];

  const int g   = tid >> 7;          // phase-A gate: 0=z, 1=r
  const int cA  = (tid >> 4) & 7;    // phase-A column within 8-col sub-block
  const int ipA = tid & 15;          // 16 lanes per column
  const int cB  = tid >> 5;          // phase-B column (0..7)
  const int ipB = tid & 31;          // 32 lanes per column
  float* hbp = &hb[0][0];
  __syncthreads();

  for (int t = 0; t < TR; ++t) {
    // prefetch gx operands for this step (L2 loads hidden under the poll)
    float gxa0 = 0.f, gxa1 = 0.f;
    if (ipA < 4) {
      const float* gp = g ? gr : gz;
      gxa0 = gp[((size_t)t * 4 + ipA) * P + j0 + cA];
      gxa1 = gp[((size_t)t * 4 + ipA) * P + j0 + 8 + cA];
    }
    float ghv0 = 0.f, ghv1 = 0.f;
    if (ipB < 4) {
      ghv0 = gh[((size_t)t * 4 + ipB) * P + j0 + cB];
      ghv1 = gh[((size_t)t * 4 + ipB) * P + j0 + 8 + cB];
    }

    // gather h(t): tagged poll, deposits into hb
    poll_slot(hT + (size_t)(t & 1) * 2048, (unsigned)t, hbp, tid);
    __syncthreads();

    // phase A: z,r for this WG's 16 columns
#pragma unroll
    for (int sub = 0; sub < 2; ++sub) {
      float a0 = 0.f, a1 = 0.f, a2 = 0.f, a3 = 0.f;
      const float* Uc = &Us[g][sub][cA][0];
#pragma unroll
      for (int n = 0; n < 8; ++n) {
        int off = ((n << 4) | ipA) << 2;
        float4 u  = *(const float4*)&Uc[off];
        float4 h0v = *(const float4*)&hb[0][off];
        float4 h1v = *(const float4*)&hb[1][off];
        float4 h2v = *(const float4*)&hb[2][off];
        float4 h3v = *(const float4*)&hb[3][off];
        a0 += u.x * h0v.x + u.y * h0v.y + u.z * h0v.z + u.w * h0v.w;
        a1 += u.x * h1v.x + u.y * h1v.y + u.z * h1v.z + u.w * h1v.w;
        a2 += u.x * h2v.x + u.y * h2v.y + u.z * h2v.z + u.w * h2v.w;
        a3 += u.x * h3v.x + u.y * h3v.y + u.z * h3v.z + u.w * h3v.w;
      }
      float v = xreduce4<4>(a0, a1, a2, a3, ipA);
      if (ipA < 4) {
        const int b = ipA;
        float s = (sub ? gxa1 : gxa0) + v;
        float sg = 1.0f / (1.0f + expf(-s));
        if (g == 0) {
          zloc[sub][b][cA] = sg;
        } else {
          float hov = hb[b][j0 + sub * 8 + cA];
          hploc[sub][b][cA] = hov;
          unsigned long long w = ((unsigned long long)(unsigned)t << 32)
                               | (unsigned long long)__float_as_uint(sg * hov);
          __hip_atomic_store(rhT + (size_t)(t & 1) * 2048 + b * 512 + j0 + sub * 8 + cA,
                             w, __ATOMIC_RELAXED, __HIP_MEMORY_SCOPE_AGENT);
        }
      }
    }
    __syncthreads();   // zloc/hploc ready; all hb(h) reads done

    // gather rh(t) into hb (overwrites h)
    poll_slot(rhT + (size_t)(t & 1) * 2048, (unsigned)t, hbp, tid);
    __syncthreads();

    // phase B: h_hat, h_new, h_out; publish tagged h(t+1)
#pragma unroll
    for (int sub = 0; sub < 2; ++sub) {
      float p0 = 0.f, p1 = 0.f, p2 = 0.f, p3 = 0.f;
      const float* Uc = &Us[2][sub][cB][0];
#pragma unroll
      for (int n = 0; n < 4; ++n) {
        int off = ((n << 5) | ipB) << 2;
        float4 u  = *(const float4*)&Uc[off];
        float4 h0v = *(const float4*)&hb[0][off];
        float4 h1v = *(const float4*)&hb[1][off];
        float4 h2v = *(const float4*)&hb[2][off];
        float4 h3v = *(const float4*)&hb[3][off];
        p0 += u.x * h0v.x + u.y * h0v.y + u.z * h0v.z + u.w * h0v.w;
        p1 += u.x * h1v.x + u.y * h1v.y + u.z * h1v.z + u.w * h1v.w;
        p2 += u.x * h2v.x + u.y * h2v.y + u.z * h2v.z + u.w * h2v.w;
        p3 += u.x * h3v.x + u.y * h3v.y + u.z * h3v.z + u.w * h3v.w;
      }
      float pv = xreduce4<5>(p0, p1, p2, p3, ipB);
      if (ipB < 4) {
        const int b = ipB;
        float hhat = tanhf((sub ? ghv1 : ghv0) + pv);
        float z = zloc[sub][b][cB], hp = hploc[sub][b][cB];
        float hn = (1.0f - z) * hp + z * hhat;
        float dtv = (t == 0) ? 0.f : DTC;
        float ho = hn + dtv * (hn - hp);
        unsigned long long w = ((unsigned long long)(unsigned)(t + 1) << 32)
                             | (unsigned long long)__float_as_uint(ho);
        __hip_atomic_store(hT + (size_t)((t + 1) & 1) * 2048 + b * 512 + j0 + sub * 8 + cB,
                           w, __ATOMIC_RELAXED, __HIP_MEMORY_SCOPE_AGENT);
        holoc[sub][b][cB] = ho;
      }
    }
    __syncthreads();   // holoc ready; all hb(rh) reads done

    // logit partial for step t (overlaps next step's poll on other lanes)
    if (tid < 32) {
      int c = tid >> 2, b = tid & 3;
      float pl = holoc[0][b][c] * wmv0 + holoc[1][b][c] * wmv1;
      pl += __shfl_xor(pl, 4);
      pl += __shfl_xor(pl, 8);
      pl += __shfl_xor(pl, 16);
      if (c == 0) {
        if (wg == 0) pl += bmv;
        atomicAdd(out + (size_t)b * TR + t, pl);
      }
    }
  }
}

extern "C" void kernel_launch(void* const* d_in, const int* in_sizes, int n_in,
                              void* d_out, int out_size, void* d_ws, size_t ws_size,
                              hipStream_t stream)
{
  const float* x      = (const float*)d_in[0];
  const float* Wq     = (const float*)d_in[1];
  const float* bq     = (const float*)d_in[2];
  const float* Wk     = (const float*)d_in[3];
  const float* bk     = (const float*)d_in[4];
  const float* Wv     = (const float*)d_in[5];
  const float* bv     = (const float*)d_in[6];
  const float* Wz     = (const float*)d_in[7];
  const float* Uz     = (const float*)d_in[8];
  const float* bz     = (const float*)d_in[9];
  const float* Wr     = (const float*)d_in[10];
  const float* Ur     = (const float*)d_in[11];
  const float* br     = (const float*)d_in[12];
  const float* Wh     = (const float*)d_in[13];
  const float* Uh     = (const float*)d_in[14];
  const float* bh     = (const float*)d_in[15];
  const float* Wmem   = (const float*)d_in[16];
  const float* bmem   = (const float*)d_in[17];
  const float* Wp2h   = (const float*)d_in[18];
  const float* bp2h   = (const float*)d_in[19];
  const float* Wscore = (const float*)d_in[20];

  float* ws  = (float*)d_ws;
  float* out = (float*)d_out;
  float* Q    = ws + OFF_Q;
  float* Kk   = ws + OFF_K;
  float* V    = ws + OFF_V;
  float* feat = ws + OFF_FEAT;
  float* Sc   = ws + OFF_SC;
  float* gz   = ws + OFF_GXZ;
  float* gr   = ws + OFF_GXR;
  float* gh   = ws + OFF_GXH;
  // Tagged sync buffers live at the head of the (dead-after-attnv) scores
  // region: hT[2][4][512] + rhT[2][4][512] as {tag:u32, f32-bits} words.
  unsigned long long* hT  = (unsigned long long*)(ws + OFF_SC);
  unsigned long long* rhT = hT + 4096;

  k_zero<<<dim3(24), 256, 0, stream>>>(out, Bb * TR);

  k_qkv<<<dim3(8, 128, 3), 256, 0, stream>>>(x, Wq, Wk, Wv, bq, bk, bv, Q, Kk, V);
  k_scores<<<dim3(32, 32, 4), 256, 0, stream>>>(Q, Kk, Sc);
  k_softmax<<<dim3(2048, 4), 256, 0, stream>>>(Sc);
  k_attnv<<<dim3(8, 32, 4), 256, 0, stream>>>(Sc, V, feat);
  // clear stale tags AFTER the scores region is dead, BEFORE k_pool writes h0
  k_tagclear<<<dim3(32), 256, 0, stream>>>(hT, 8192);
  k_gx<<<dim3(8, 96, 3), 256, 0, stream>>>(feat, Wz, Wr, Wh, bz, br, bh, gz, gr, gh);
  k_pool<<<dim3(4), 256, 0, stream>>>(feat, Wscore, Wp2h, bp2h, hT);
  k_scan<<<dim3(NWG), 256, 0, stream>>>(Uz, Ur, Uh, gz, gr, gh, Wmem, bmem,
                                        hT, rhT, out);
}

// Round 3
// 9450.073 us; speedup vs baseline: 1.7434x; 1.7434x over previous
//
#include <hip/hip_runtime.h>
#include <cmath>

// Problem constants
static constexpr int Bb  = 4;
static constexpr int S   = 2048;
static constexpr int DIN = 4096;
static constexpr int P   = 512;    // D_PROJ == D_MEM
static constexpr int AST = 512;    // assistant_start
static constexpr int TR  = 1536;   // run length
static constexpr int NWG = 32;     // scan workgroups (16 U-columns each)
#define DTC (1.0f/1535.0f)

// Workspace layout (float element offsets)
static constexpr size_t SZ      = (size_t)Bb * S * P;          // 4,194,304
static constexpr size_t GXSZ    = (size_t)TR * Bb * P;         // 3,145,728
static constexpr size_t OFF_Q   = 0;
static constexpr size_t OFF_K   = SZ;
static constexpr size_t OFF_V   = 2 * SZ;
static constexpr size_t OFF_GXZ = 0;                           // reuses Q/K/V after attention
static constexpr size_t OFF_GXR = GXSZ;
static constexpr size_t OFF_GXH = 2 * GXSZ;
static constexpr size_t OFF_FEAT= 3 * GXSZ + (size_t)(TR + 1) * Bb * P;
static constexpr size_t OFF_SC  = OFF_FEAT + SZ;               // scores; tagged bufs + part live here in scan phase
static constexpr size_t OFF_PART= OFF_SC + 16384;              // after hT/rhT (8192 u64 = 16384 floats)

#define INNER16 \
  acc[0][0] += af.x*bf.x; acc[0][1] += af.x*bf.y; acc[0][2] += af.x*bf.z; acc[0][3] += af.x*bf.w; \
  acc[1][0] += af.y*bf.x; acc[1][1] += af.y*bf.y; acc[1][2] += af.y*bf.z; acc[1][3] += af.y*bf.w; \
  acc[2][0] += af.z*bf.x; acc[2][1] += af.z*bf.y; acc[2][2] += af.z*bf.z; acc[2][3] += af.z*bf.w; \
  acc[3][0] += af.w*bf.x; acc[3][1] += af.w*bf.y; acc[3][2] += af.w*bf.z; acc[3][3] += af.w*bf.w;

// Fill tagged-word buffers with an impossible tag (0xFFFFFFFF) so stale data
// from a previous launch/graph-replay can never match a step tag.
__global__ __launch_bounds__(256) void k_tagclear(unsigned long long* p, int n) {
  int i = blockIdx.x * 256 + threadIdx.x;
  if (i < n) p[i] = 0xFFFFFFFF00000000ULL;
}

// ---------------- QKV projection: (8192 x 4096) @ (4096 x 512) + bias, z selects Q/K/V
__global__ __launch_bounds__(256) void k_qkv(
    const float* __restrict__ x,
    const float* __restrict__ W0, const float* __restrict__ W1, const float* __restrict__ W2,
    const float* __restrict__ b0, const float* __restrict__ b1, const float* __restrict__ b2,
    float* __restrict__ O0, float* __restrict__ O1, float* __restrict__ O2)
{
  __shared__ float As[32][68];  // transposed A tile: As[k][m]
  __shared__ float Bs[32][64];
  const int z = blockIdx.z;
  const float* W    = (z == 0) ? W0 : (z == 1) ? W1 : W2;
  const float* bias = (z == 0) ? b0 : (z == 1) ? b1 : b2;
  float* Out        = (z == 0) ? O0 : (z == 1) ? O1 : O2;
  const int tid = threadIdx.x;
  const int m0 = blockIdx.y * 64, n0 = blockIdx.x * 64;
  const int tm = tid >> 4, tn = tid & 15;
  const int la_m = tid >> 3;
  const int la_k = (tid & 7) << 2;
  const int lb_k = tid >> 4;
  const int lb_n = (tid & 15) << 2;
  float acc[4][4] = {};
  for (int k0 = 0; k0 < DIN; k0 += 32) {
#pragma unroll
    for (int pp = 0; pp < 2; ++pp) {
      int m = la_m + pp * 32;
      float4 v = *(const float4*)(x + (size_t)(m0 + m) * DIN + k0 + la_k);
      As[la_k + 0][m] = v.x; As[la_k + 1][m] = v.y; As[la_k + 2][m] = v.z; As[la_k + 3][m] = v.w;
    }
#pragma unroll
    for (int pp = 0; pp < 2; ++pp) {
      int k = lb_k + pp * 16;
      *(float4*)&Bs[k][lb_n] = *(const float4*)(W + (size_t)(k0 + k) * P + n0 + lb_n);
    }
    __syncthreads();
#pragma unroll
    for (int kk = 0; kk < 32; ++kk) {
      float4 af = *(float4*)&As[kk][tm << 2];
      float4 bf = *(float4*)&Bs[kk][tn << 2];
      INNER16
    }
    __syncthreads();
  }
  float4 bv = *(const float4*)(bias + n0 + (tn << 2));
#pragma unroll
  for (int i = 0; i < 4; ++i) {
    int row = m0 + (tm << 2) + i;
    float4 o = make_float4(acc[i][0] + bv.x, acc[i][1] + bv.y, acc[i][2] + bv.z, acc[i][3] + bv.w);
    *(float4*)(Out + (size_t)row * P + n0 + (tn << 2)) = o;
  }
}

// ---------------- scores = Q @ K^T / scale, causal mask (only tiles jt <= qt computed)
__global__ __launch_bounds__(256) void k_scores(
    const float* __restrict__ Q, const float* __restrict__ Km, float* __restrict__ Sc)
{
  const int jt = blockIdx.x, qt = blockIdx.y, b = blockIdx.z;
  if (jt > qt) return;
  __shared__ float As[32][68];  // Q^T: As[k][i]
  __shared__ float Bs[32][68];  // K^T: Bs[k][j]
  const float* Qb = Q + (size_t)b * S * P;
  const float* Kb = Km + (size_t)b * S * P;
  const int tid = threadIdx.x;
  const int i0 = qt * 64, j0 = jt * 64;
  const int tm = tid >> 4, tn = tid & 15;
  const int lr = tid >> 3;
  const int lk = (tid & 7) << 2;
  float acc[4][4] = {};
  for (int k0 = 0; k0 < P; k0 += 32) {
#pragma unroll
    for (int pp = 0; pp < 2; ++pp) {
      int r = lr + pp * 32;
      float4 v = *(const float4*)(Qb + (size_t)(i0 + r) * P + k0 + lk);
      As[lk + 0][r] = v.x; As[lk + 1][r] = v.y; As[lk + 2][r] = v.z; As[lk + 3][r] = v.w;
      float4 w = *(const float4*)(Kb + (size_t)(j0 + r) * P + k0 + lk);
      Bs[lk + 0][r] = w.x; Bs[lk + 1][r] = w.y; Bs[lk + 2][r] = w.z; Bs[lk + 3][r] = w.w;
    }
    __syncthreads();
#pragma unroll
    for (int kk = 0; kk < 32; ++kk) {
      float4 af = *(float4*)&As[kk][tm << 2];
      float4 bf = *(float4*)&Bs[kk][tn << 2];
      INNER16
    }
    __syncthreads();
  }
  const float invs = 0.04419417382f;  // 1/sqrt(512+1e-6)
#pragma unroll
  for (int i = 0; i < 4; ++i) {
    int ig = i0 + (tm << 2) + i;
    float v0 = acc[i][0] * invs, v1 = acc[i][1] * invs, v2 = acc[i][2] * invs, v3 = acc[i][3] * invs;
    int jg = j0 + (tn << 2);
    if (jg + 0 > ig) v0 = -1e9f;
    if (jg + 1 > ig) v1 = -1e9f;
    if (jg + 2 > ig) v2 = -1e9f;
    if (jg + 3 > ig) v3 = -1e9f;
    *(float4*)(Sc + (size_t)b * S * S + (size_t)ig * S + jg) = make_float4(v0, v1, v2, v3);
  }
}

// ---------------- row softmax over [0, i], zero-fill to end of diagonal tile (in place)
__global__ __launch_bounds__(256) void k_softmax(float* __restrict__ Sc)
{
  const int i = blockIdx.x, b = blockIdx.y;
  float* row = Sc + (size_t)b * S * S + (size_t)i * S;
  __shared__ float sv[2048];
  __shared__ float red[256];
  const int tid = threadIdx.x;
  const int len = i + 1;
  float lmax = -1e30f;
  for (int k = tid; k < len; k += 256) { float v = row[k]; sv[k] = v; lmax = fmaxf(lmax, v); }
  red[tid] = lmax; __syncthreads();
  for (int s = 128; s > 0; s >>= 1) { if (tid < s) red[tid] = fmaxf(red[tid], red[tid + s]); __syncthreads(); }
  const float m = red[0]; __syncthreads();
  float lsum = 0.f;
  for (int k = tid; k < len; k += 256) { float e = expf(sv[k] - m); sv[k] = e; lsum += e; }
  red[tid] = lsum; __syncthreads();
  for (int s = 128; s > 0; s >>= 1) { if (tid < s) red[tid] += red[tid + s]; __syncthreads(); }
  const float inv = 1.0f / red[0];
  for (int k = tid; k < len; k += 256) row[k] = sv[k] * inv;
  const int tail = ((i >> 6) + 1) << 6;
  for (int k = len + tid; k < tail; k += 256) row[k] = 0.f;
}

// ---------------- feat = attn @ V (skip upper-triangle tiles)
__global__ __launch_bounds__(256) void k_attnv(
    const float* __restrict__ At, const float* __restrict__ V, float* __restrict__ F)
{
  __shared__ float As[32][68];
  __shared__ float Bs[32][64];
  const int qt = blockIdx.y, b = blockIdx.z;
  const float* Ab = At + (size_t)b * S * S;
  const float* Vb = V + (size_t)b * S * P;
  const int tid = threadIdx.x;
  const int m0 = qt * 64, n0 = blockIdx.x * 64;
  const int tm = tid >> 4, tn = tid & 15;
  const int la_m = tid >> 3;
  const int la_k = (tid & 7) << 2;
  const int lb_k = tid >> 4;
  const int lb_n = (tid & 15) << 2;
  float acc[4][4] = {};
  const int kext = (qt + 1) * 64;
  for (int k0 = 0; k0 < kext; k0 += 32) {
#pragma unroll
    for (int pp = 0; pp < 2; ++pp) {
      int m = la_m + pp * 32;
      float4 v = *(const float4*)(Ab + (size_t)(m0 + m) * S + k0 + la_k);
      As[la_k + 0][m] = v.x; As[la_k + 1][m] = v.y; As[la_k + 2][m] = v.z; As[la_k + 3][m] = v.w;
    }
#pragma unroll
    for (int pp = 0; pp < 2; ++pp) {
      int k = lb_k + pp * 16;
      *(float4*)&Bs[k][lb_n] = *(const float4*)(Vb + (size_t)(k0 + k) * P + n0 + lb_n);
    }
    __syncthreads();
#pragma unroll
    for (int kk = 0; kk < 32; ++kk) {
      float4 af = *(float4*)&As[kk][tm << 2];
      float4 bf = *(float4*)&Bs[kk][tn << 2];
      INNER16
    }
    __syncthreads();
  }
#pragma unroll
  for (int i = 0; i < 4; ++i) {
    int row = m0 + (tm << 2) + i;
    *(float4*)(F + (size_t)b * S * P + (size_t)row * P + n0 + (tn << 2)) =
        make_float4(acc[i][0], acc[i][1], acc[i][2], acc[i][3]);
  }
}

// ---------------- gx = feat_assist @ {Wz,Wr,Wh} + bias; output layout [t][b][j]
__global__ __launch_bounds__(256) void k_gx(
    const float* __restrict__ feat,
    const float* __restrict__ Wz, const float* __restrict__ Wr, const float* __restrict__ Wh,
    const float* __restrict__ bz, const float* __restrict__ br, const float* __restrict__ bh,
    float* __restrict__ gz, float* __restrict__ gr, float* __restrict__ gh)
{
  __shared__ float As[32][68];
  __shared__ float Bs[32][64];
  const int z = blockIdx.z;
  const float* W    = (z == 0) ? Wz : (z == 1) ? Wr : Wh;
  const float* bias = (z == 0) ? bz : (z == 1) ? br : bh;
  float* Out        = (z == 0) ? gz : (z == 1) ? gr : gh;
  const int tid = threadIdx.x;
  const int m0 = blockIdx.y * 64, n0 = blockIdx.x * 64;
  const int bb = m0 / TR;
  const int t0 = m0 - bb * TR;
  const float* Arow = feat + ((size_t)(bb * S + AST + t0)) * P;  // 64 consecutive rows
  const int tm = tid >> 4, tn = tid & 15;
  const int la_m = tid >> 3;
  const int la_k = (tid & 7) << 2;
  const int lb_k = tid >> 4;
  const int lb_n = (tid & 15) << 2;
  float acc[4][4] = {};
  for (int k0 = 0; k0 < P; k0 += 32) {
#pragma unroll
    for (int pp = 0; pp < 2; ++pp) {
      int m = la_m + pp * 32;
      float4 v = *(const float4*)(Arow + (size_t)m * P + k0 + la_k);
      As[la_k + 0][m] = v.x; As[la_k + 1][m] = v.y; As[la_k + 2][m] = v.z; As[la_k + 3][m] = v.w;
    }
#pragma unroll
    for (int pp = 0; pp < 2; ++pp) {
      int k = lb_k + pp * 16;
      *(float4*)&Bs[k][lb_n] = *(const float4*)(W + (size_t)(k0 + k) * P + n0 + lb_n);
    }
    __syncthreads();
#pragma unroll
    for (int kk = 0; kk < 32; ++kk) {
      float4 af = *(float4*)&As[kk][tm << 2];
      float4 bf = *(float4*)&Bs[kk][tn << 2];
      INNER16
    }
    __syncthreads();
  }
  float4 bv = *(const float4*)(bias + n0 + (tn << 2));
#pragma unroll
  for (int i = 0; i < 4; ++i) {
    int t = t0 + (tm << 2) + i;
    float4 o = make_float4(acc[i][0] + bv.x, acc[i][1] + bv.y, acc[i][2] + bv.z, acc[i][3] + bv.w);
    *(float4*)(Out + ((size_t)t * 4 + bb) * P + n0 + (tn << 2)) = o;
  }
}

// ---------------- attention pooling over prefix + h0; writes tagged h(0) (tag=0)
__global__ __launch_bounds__(256) void k_pool(
    const float* __restrict__ feat, const float* __restrict__ Wscore,
    const float* __restrict__ Wp2h, const float* __restrict__ bp2h,
    unsigned long long* __restrict__ hT)
{
  const int b = blockIdx.x;
  const float* fb = feat + (size_t)b * S * P;  // prefix rows 0..511
  __shared__ float sw[512];
  __shared__ float pool[512];
  __shared__ float red[256];
  const int tid = threadIdx.x;
  for (int u = tid; u < 512; u += 256) {
    float s = 0.f;
    for (int p4 = 0; p4 < P; p4 += 4) {
      float4 f = *(const float4*)(fb + (size_t)u * P + p4);
      float4 w = *(const float4*)(Wscore + p4);
      s += f.x * w.x + f.y * w.y + f.z * w.z + f.w * w.w;
    }
    sw[u] = s;
  }
  __syncthreads();
  float lm = fmaxf(sw[tid], sw[tid + 256]);
  red[tid] = lm; __syncthreads();
  for (int s = 128; s > 0; s >>= 1) { if (tid < s) red[tid] = fmaxf(red[tid], red[tid + s]); __syncthreads(); }
  const float m = red[0]; __syncthreads();
  float e0 = expf(sw[tid] - m), e1 = expf(sw[tid + 256] - m);
  sw[tid] = e0; sw[tid + 256] = e1;
  red[tid] = e0 + e1; __syncthreads();
  for (int s = 128; s > 0; s >>= 1) { if (tid < s) red[tid] += red[tid + s]; __syncthreads(); }
  const float inv = 1.0f / red[0];
  __syncthreads();
  sw[tid] *= inv; sw[tid + 256] *= inv;
  __syncthreads();
  for (int p = tid; p < P; p += 256) {
    float a = 0.f;
    for (int u = 0; u < 512; ++u) a += sw[u] * fb[(size_t)u * P + p];
    pool[p] = a;
  }
  __syncthreads();
  for (int j = tid; j < P; j += 256) {
    float a = bp2h[j];
    for (int p = 0; p < P; ++p) a += pool[p] * Wp2h[(size_t)p * P + j];
    // tagged word: tag (hi) = 0, value (lo) = f32 bits of h0
    hT[(size_t)b * 512 + j] = (unsigned long long)__float_as_uint(tanhf(a));
  }
}

// xor-butterfly reduce of 4 batch accumulators across a 2^LOG2N-lane group.
// Result: group-lane l holds acc[l&3] summed over the whole group.
template<int LOG2N>
__device__ __forceinline__ float xreduce4(float a0, float a1, float a2, float a3, int lane)
{
  float s01 = (lane & 1) ? a0 : a1;
  float r01 = __shfl_xor(s01, 1);
  float x0  = ((lane & 1) ? a1 : a0) + r01;
  float s23 = (lane & 1) ? a2 : a3;
  float r23 = __shfl_xor(s23, 1);
  float x2  = ((lane & 1) ? a3 : a2) + r23;
  float s   = (lane & 2) ? x0 : x2;
  float r   = __shfl_xor(s, 2);
  float v   = ((lane & 2) ? x2 : x0) + r;
#pragma unroll
  for (int m = 4; m < (1 << LOG2N); m <<= 1) v += __shfl_xor(v, m);
  return v;
}

// ---------------- persistent GRU scan: 32 WGs x 512 threads, 16 U-columns each.
// Cross-WG sync: tagged 8-byte words ({step : f32}) in a depth-2 double buffer
// at AGENT scope. Each thread owns 4 consecutive broadcast floats which come
// from exactly ONE writer WG; it polls only those 4 words and exits as soon
// as its writer lands. HANG-SAFETY INVARIANT: every poll is separated from
// the same WG's corresponding publish stores by a __syncthreads() (vmcnt(0)
// drain), so a WG can never spin on a store it has not yet issued. Depth-2
// buffer safety: h(t+2)/rh(t+2) publish transitively requires every WG to
// have fully consumed h(t)/rh(t) (two interleaved all-gathers in between).
__global__ __launch_bounds__(512) void k_scan(
    const float* __restrict__ Uz, const float* __restrict__ Ur, const float* __restrict__ Uh,
    const float* __restrict__ gz, const float* __restrict__ gr, const float* __restrict__ gh,
    const float* __restrict__ Wmem,
    unsigned long long* __restrict__ hT, unsigned long long* __restrict__ rhT,
    float* __restrict__ part)
{
  __shared__ float Us[3][2][8][520];
  __shared__ float hb[4][516];
  __shared__ float zloc[16][4];
  __shared__ float hploc[16][4];
  __shared__ float holoc[16][4];
  const int wg = blockIdx.x;
  const int tid = threadIdx.x;
  const int j0 = wg * 16;

  for (int idx = tid; idx < 3 * 512 * 16; idx += 512) {
    int mt = idx >> 13;                // 8192 elements per matrix
    int rem = idx & 8191;
    int i = rem >> 4, c = rem & 15;
    const float* U = (mt == 0) ? Uz : (mt == 1) ? Ur : Uh;
    Us[mt][c >> 3][c & 7][i] = U[(size_t)i * P + j0 + c];
  }
  float wmv = 0.f;
  if (tid < 64) wmv = Wmem[j0 + (tid >> 2)];

  // phase-A role: gate g (0=z,1=r), column cAa (0..15), 16 lanes per column
  const int gA  = tid >> 8;
  const int cAa = (tid >> 4) & 15;
  const int ipA = tid & 15;
  const float* UcA = &Us[gA][cAa >> 3][cAa & 7][0];
  // phase-B role: column cBb (0..15), 32 lanes per column
  const int cBb = tid >> 5;
  const int ipB = tid & 31;
  const float* UcB = &Us[2][cBb >> 3][cBb & 7][0];
  // poll role: 4 consecutive floats, single writer WG
  const int pb = tid >> 7;
  const int pj = (tid << 2) & 511;
  float* dep = &hb[pb][pj];
  __syncthreads();

  for (int t = 0; t < TR; ++t) {
    const unsigned long long wtag = (unsigned long long)(unsigned)t << 32;
    // prefetch gx operands (L2 loads, hidden under the h poll)
    float gxa = 0.f;
    if (ipA < 4) gxa = (gA ? gr : gz)[((size_t)t * 4 + ipA) * P + j0 + cAa];
    float ghv = 0.f;
    if (ipB < 4) ghv = gh[((size_t)t * 4 + ipB) * P + j0 + cBb];

    // gather h(t): poll own 4 tagged words, deposit to LDS.
    // (own-WG h(t) stores were drained by the previous iteration's barrier /
    //  written by k_pool for t=0 — no self-wait possible)
    {
      const unsigned long long* src = hT + (size_t)(t & 1) * 2048 + ((size_t)tid << 2);
      unsigned long long u0, u1, u2, u3;
      do {
        u0 = __hip_atomic_load(src + 0, __ATOMIC_RELAXED, __HIP_MEMORY_SCOPE_AGENT);
        u1 = __hip_atomic_load(src + 1, __ATOMIC_RELAXED, __HIP_MEMORY_SCOPE_AGENT);
        u2 = __hip_atomic_load(src + 2, __ATOMIC_RELAXED, __HIP_MEMORY_SCOPE_AGENT);
        u3 = __hip_atomic_load(src + 3, __ATOMIC_RELAXED, __HIP_MEMORY_SCOPE_AGENT);
      } while ((((u0 ^ wtag) | (u1 ^ wtag) | (u2 ^ wtag) | (u3 ^ wtag)) >> 32) != 0ull);
      *(float4*)dep = make_float4(__uint_as_float((unsigned)u0), __uint_as_float((unsigned)u1),
                                  __uint_as_float((unsigned)u2), __uint_as_float((unsigned)u3));
    }
    __syncthreads();   // B1: hb holds h(t)

    // phase A: z,r for this WG's 16 columns (one column per 16-lane group)
    {
      float a0 = 0.f, a1 = 0.f, a2 = 0.f, a3 = 0.f;
#pragma unroll
      for (int n = 0; n < 8; ++n) {
        int off = ((n << 4) | ipA) << 2;
        float4 u   = *(const float4*)&UcA[off];
        float4 h0v = *(const float4*)&hb[0][off];
        float4 h1v = *(const float4*)&hb[1][off];
        float4 h2v = *(const float4*)&hb[2][off];
        float4 h3v = *(const float4*)&hb[3][off];
        a0 += u.x * h0v.x + u.y * h0v.y + u.z * h0v.z + u.w * h0v.w;
        a1 += u.x * h1v.x + u.y * h1v.y + u.z * h1v.z + u.w * h1v.w;
        a2 += u.x * h2v.x + u.y * h2v.y + u.z * h2v.z + u.w * h2v.w;
        a3 += u.x * h3v.x + u.y * h3v.y + u.z * h3v.z + u.w * h3v.w;
      }
      float v = xreduce4<4>(a0, a1, a2, a3, ipA);
      if (ipA < 4) {
        const int b = ipA;
        float s = gxa + v;
        float sg = 1.0f / (1.0f + expf(-s));
        if (gA == 0) {
          zloc[cAa][b] = sg;
        } else {
          float hov = hb[b][j0 + cAa];
          hploc[cAa][b] = hov;
          unsigned long long w = wtag | (unsigned long long)__float_as_uint(sg * hov);
          __hip_atomic_store(rhT + (size_t)(t & 1) * 2048 + (size_t)b * 512 + j0 + cAa,
                             w, __ATOMIC_RELAXED, __HIP_MEMORY_SCOPE_AGENT);
        }
      }
      asm volatile("" ::: "memory");  // keep the rh publish above the barrier
    }
    __syncthreads();   // B2: zloc/hploc visible; rh stores DRAINED (vmcnt 0);
                       //     all hb(h) reads complete

    // gather rh(t): poll own 4 tagged words (own-WG stores already drained),
    // deposit straight into hb (h reads finished at B2)
    {
      const unsigned long long* src = rhT + (size_t)(t & 1) * 2048 + ((size_t)tid << 2);
      unsigned long long r0, r1, r2, r3;
      do {
        r0 = __hip_atomic_load(src + 0, __ATOMIC_RELAXED, __HIP_MEMORY_SCOPE_AGENT);
        r1 = __hip_atomic_load(src + 1, __ATOMIC_RELAXED, __HIP_MEMORY_SCOPE_AGENT);
        r2 = __hip_atomic_load(src + 2, __ATOMIC_RELAXED, __HIP_MEMORY_SCOPE_AGENT);
        r3 = __hip_atomic_load(src + 3, __ATOMIC_RELAXED, __HIP_MEMORY_SCOPE_AGENT);
      } while ((((r0 ^ wtag) | (r1 ^ wtag) | (r2 ^ wtag) | (r3 ^ wtag)) >> 32) != 0ull);
      *(float4*)dep = make_float4(__uint_as_float((unsigned)r0), __uint_as_float((unsigned)r1),
                                  __uint_as_float((unsigned)r2), __uint_as_float((unsigned)r3));
    }
    __syncthreads();   // B3: hb holds rh(t)

    // phase B: h_hat, h_new, h_out; publish tagged h(t+1)
    {
      float p0 = 0.f, p1 = 0.f, p2 = 0.f, p3 = 0.f;
#pragma unroll
      for (int n = 0; n < 4; ++n) {
        int off = ((n << 5) | ipB) << 2;
        float4 u   = *(const float4*)&UcB[off];
        float4 h0v = *(const float4*)&hb[0][off];
        float4 h1v = *(const float4*)&hb[1][off];
        float4 h2v = *(const float4*)&hb[2][off];
        float4 h3v = *(const float4*)&hb[3][off];
        p0 += u.x * h0v.x + u.y * h0v.y + u.z * h0v.z + u.w * h0v.w;
        p1 += u.x * h1v.x + u.y * h1v.y + u.z * h1v.z + u.w * h1v.w;
        p2 += u.x * h2v.x + u.y * h2v.y + u.z * h2v.z + u.w * h2v.w;
        p3 += u.x * h3v.x + u.y * h3v.y + u.z * h3v.z + u.w * h3v.w;
      }
      float pv = xreduce4<5>(p0, p1, p2, p3, ipB);
      if (ipB < 4) {
        const int b = ipB;
        float hhat = tanhf(ghv + pv);
        float z = zloc[cBb][b], hp = hploc[cBb][b];
        float hn = (1.0f - z) * hp + z * hhat;
        float dtv = (t == 0) ? 0.f : DTC;
        float ho = hn + dtv * (hn - hp);
        unsigned long long w = ((unsigned long long)(unsigned)(t + 1) << 32)
                             | (unsigned long long)__float_as_uint(ho);
        __hip_atomic_store(hT + (size_t)((t + 1) & 1) * 2048 + (size_t)b * 512 + j0 + cBb,
                           w, __ATOMIC_RELAXED, __HIP_MEMORY_SCOPE_AGENT);
        holoc[cBb][b] = ho;
      }
      asm volatile("" ::: "memory");  // keep the h publish above the barrier
    }
    __syncthreads();   // B4: holoc visible; h(t+1) stores DRAINED;
                       //     all hb(rh) reads complete

    // per-WG logit partial: plain store, no atomics, off the sync path
    if (tid < 64) {
      float pl = holoc[tid >> 2][tid & 3] * wmv;
      pl += __shfl_xor(pl, 4);
      pl += __shfl_xor(pl, 8);
      pl += __shfl_xor(pl, 16);
      pl += __shfl_xor(pl, 32);
      if (tid < 4) part[((size_t)tid * TR + t) * 32 + wg] = pl;
    }
  }
}

// ---------------- final reduce: out[b][t] = bmem + sum_w part[b][t][w]
__global__ __launch_bounds__(256) void k_outred(
    const float* __restrict__ part, const float* __restrict__ bmem, float* __restrict__ out)
{
  int i = blockIdx.x * 256 + threadIdx.x;
  if (i < Bb * TR) {
    const float* p = part + (size_t)i * 32;
    float s = bmem[0];
#pragma unroll
    for (int w = 0; w < 32; ++w) s += p[w];
    out[i] = s;
  }
}

extern "C" void kernel_launch(void* const* d_in, const int* in_sizes, int n_in,
                              void* d_out, int out_size, void* d_ws, size_t ws_size,
                              hipStream_t stream)
{
  const float* x      = (const float*)d_in[0];
  const float* Wq     = (const float*)d_in[1];
  const float* bq     = (const float*)d_in[2];
  const float* Wk     = (const float*)d_in[3];
  const float* bk     = (const float*)d_in[4];
  const float* Wv     = (const float*)d_in[5];
  const float* bv     = (const float*)d_in[6];
  const float* Wz     = (const float*)d_in[7];
  const float* Uz     = (const float*)d_in[8];
  const float* bz     = (const float*)d_in[9];
  const float* Wr     = (const float*)d_in[10];
  const float* Ur     = (const float*)d_in[11];
  const float* br     = (const float*)d_in[12];
  const float* Wh     = (const float*)d_in[13];
  const float* Uh     = (const float*)d_in[14];
  const float* bh     = (const float*)d_in[15];
  const float* Wmem   = (const float*)d_in[16];
  const float* bmem   = (const float*)d_in[17];
  const float* Wp2h   = (const float*)d_in[18];
  const float* bp2h   = (const float*)d_in[19];
  const float* Wscore = (const float*)d_in[20];

  float* ws  = (float*)d_ws;
  float* out = (float*)d_out;
  float* Q    = ws + OFF_Q;
  float* Kk   = ws + OFF_K;
  float* V    = ws + OFF_V;
  float* feat = ws + OFF_FEAT;
  float* Sc   = ws + OFF_SC;
  float* gz   = ws + OFF_GXZ;
  float* gr   = ws + OFF_GXR;
  float* gh   = ws + OFF_GXH;
  // Tagged sync buffers + per-WG logit partials live at the head of the
  // (dead-after-attnv) scores region.
  unsigned long long* hT   = (unsigned long long*)(ws + OFF_SC);
  unsigned long long* rhT  = hT + 4096;
  float*              prt  = ws + OFF_PART;

  k_qkv<<<dim3(8, 128, 3), 256, 0, stream>>>(x, Wq, Wk, Wv, bq, bk, bv, Q, Kk, V);
  k_scores<<<dim3(32, 32, 4), 256, 0, stream>>>(Q, Kk, Sc);
  k_softmax<<<dim3(2048, 4), 256, 0, stream>>>(Sc);
  k_attnv<<<dim3(8, 32, 4), 256, 0, stream>>>(Sc, V, feat);
  // clear stale tags AFTER the scores region is dead, BEFORE k_pool writes h0
  k_tagclear<<<dim3(32), 256, 0, stream>>>(hT, 8192);
  k_gx<<<dim3(8, 96, 3), 256, 0, stream>>>(feat, Wz, Wr, Wh, bz, br, bh, gz, gr, gh);
  k_pool<<<dim3(4), 256, 0, stream>>>(feat, Wscore, Wp2h, bp2h, hT);
  k_scan<<<dim3(NWG), 512, 0, stream>>>(Uz, Ur, Uh, gz, gr, gh, Wmem, hT, rhT, prt);
  k_outred<<<dim3(24), 256, 0, stream>>>(prt, bmem, out);
}